// Round 9
// baseline (367.943 us; speedup 1.0000x reference)
//
#include <hip/hip_runtime.h>
#include <stdint.h>

#define EMB   768
#define BATCH 8
#define SEQ   2048
#define ROWS  (BATCH*SEQ)     // 16384
#define EPS   1e-5f

#define BM 128
#define BN 128
#define BK 32
#define BK2 64

typedef _Float16 half8 __attribute__((ext_vector_type(8)));
typedef _Float16 half4 __attribute__((ext_vector_type(4)));
typedef float    floatx4 __attribute__((ext_vector_type(4)));

// async global->LDS, 16B per lane (global_load_lds_dwordx4).
__device__ __forceinline__ void g2l16(const void* g, void* l) {
    __builtin_amdgcn_global_load_lds(
        (const __attribute__((address_space(1))) unsigned int*)g,
        (__attribute__((address_space(3))) unsigned int*)l,
        16, 0, 0);
}

// ---------------- split weights: f32 -> f16 hi/lo planes ----------------
__global__ __launch_bounds__(256) void split_w_kernel(
    const float* __restrict__ wq, const float* __restrict__ wk,
    _Float16* __restrict__ wq_hi, _Float16* __restrict__ wq_lo,
    _Float16* __restrict__ wk_hi, _Float16* __restrict__ wk_lo)
{
    const float* src = (blockIdx.y == 0) ? wq : wk;
    _Float16* dh     = (blockIdx.y == 0) ? wq_hi : wk_hi;
    _Float16* dl     = (blockIdx.y == 0) ? wq_lo : wk_lo;
    int i4 = blockIdx.x * 256 + threadIdx.x;
    float4 v = ((const float4*)src)[i4];
    half4 vh, vl;
    float c[4] = {v.x, v.y, v.z, v.w};
#pragma unroll
    for (int t = 0; t < 4; t++) {
        _Float16 hi = (_Float16)c[t];
        vh[t] = hi;
        vl[t] = (_Float16)(c[t] - (float)hi);
    }
    ((half4*)dh)[i4] = vh;
    ((half4*)dl)[i4] = vl;
}

// ---------------- wtilde = Wk @ bq ----------------
__global__ __launch_bounds__(256) void wtilde_kernel(
    const float* __restrict__ wk, const float* __restrict__ bq,
    float* __restrict__ wt)
{
    int row  = blockIdx.x * 4 + (threadIdx.x >> 6);
    int lane = threadIdx.x & 63;
    const float4* r4 = (const float4*)(wk + (size_t)row * EMB);
    const float4* b4 = (const float4*)bq;
    float s = 0.f;
#pragma unroll
    for (int j = 0; j < 3; j++) {
        float4 a = r4[lane + j * 64];
        float4 b = b4[lane + j * 64];
        s += a.x * b.x + a.y * b.y + a.z * b.z + a.w * b.w;
    }
#pragma unroll
    for (int sh = 1; sh < 64; sh <<= 1) s += __shfl_xor(s, sh, 64);
    if (lane == 0) wt[row] = s;
}

// ---------------- LayerNorm: f32 in -> f16 hi only, + v = hn . wtilde -------
__global__ __launch_bounds__(256) void ln_kernel(
    const float* __restrict__ h,
    const float* __restrict__ gamma,
    const float* __restrict__ beta,
    const float* __restrict__ wt,
    _Float16* __restrict__ hn_hi,
    float* __restrict__ v_out)
{
    int row  = blockIdx.x * 4 + (threadIdx.x >> 6);
    int lane = threadIdx.x & 63;
    const float4* hr4 = (const float4*)(h + (size_t)row * EMB);
    float4 x[3];
    float s1 = 0.f, s2 = 0.f;
#pragma unroll
    for (int j = 0; j < 3; j++) {
        x[j] = hr4[lane + j * 64];
        s1 += x[j].x + x[j].y + x[j].z + x[j].w;
        s2 += x[j].x * x[j].x + x[j].y * x[j].y + x[j].z * x[j].z + x[j].w * x[j].w;
    }
#pragma unroll
    for (int s = 1; s < 64; s <<= 1) {
        s1 += __shfl_xor(s1, s, 64);
        s2 += __shfl_xor(s2, s, 64);
    }
    float mu  = s1 * (1.0f / EMB);
    float var = s2 * (1.0f / EMB) - mu * mu;
    float rs  = rsqrtf(var + EPS);
    _Float16* oh = hn_hi + (size_t)row * EMB;
    float vsum = 0.f;
#pragma unroll
    for (int j = 0; j < 3; j++) {
        int e4 = lane + j * 64;
        float4 g = ((const float4*)gamma)[e4];
        float4 b = ((const float4*)beta)[e4];
        float4 w = ((const float4*)wt)[e4];
        float v[4] = {
            (x[j].x - mu) * rs * g.x + b.x,
            (x[j].y - mu) * rs * g.y + b.y,
            (x[j].z - mu) * rs * g.z + b.z,
            (x[j].w - mu) * rs * g.w + b.w };
        vsum += v[0] * w.x + v[1] * w.y + v[2] * w.z + v[3] * w.w;
        half4 vh;
#pragma unroll
        for (int t = 0; t < 4; t++) vh[t] = (_Float16)v[t];
        *(half4*)(oh + e4 * 4) = vh;
    }
#pragma unroll
    for (int s = 1; s < 64; s <<= 1) vsum += __shfl_xor(vsum, s, 64);
    if (lane == 0) v_out[row] = vsum;
}

// ---------------- GT = Wk @ Wq^T, 64x64 tiles, output -> concatenated rows --
// gt_cat row j (length 1536): [hi row j | lo row j]. Enables K-stacked t GEMM.
__global__ __launch_bounds__(256) void gt_kernel(
    const _Float16* __restrict__ wk_hi, const _Float16* __restrict__ wk_lo,
    const _Float16* __restrict__ wq_hi, const _Float16* __restrict__ wq_lo,
    _Float16* __restrict__ gt_cat)
{
    __shared__ __attribute__((aligned(16))) _Float16 Ah_s[64 * BK];
    __shared__ __attribute__((aligned(16))) _Float16 Al_s[64 * BK];
    __shared__ __attribute__((aligned(16))) _Float16 Bh_s[64 * BK];
    __shared__ __attribute__((aligned(16))) _Float16 Bl_s[64 * BK];

    int rowbase = blockIdx.y * 64;
    int colbase = blockIdx.x * 64;
    int tid  = threadIdx.x;
    int lane = tid & 63, wave = tid >> 6;
    int wrow = (wave >> 1) * 32, wcol = (wave & 1) * 32;

    floatx4 acc[2][2];
#pragma unroll
    for (int i = 0; i < 2; i++)
#pragma unroll
        for (int j = 0; j < 2; j++) acc[i][j] = (floatx4){0.f, 0.f, 0.f, 0.f};

    size_t arow = (size_t)(rowbase + (tid >> 2)) * EMB;
    size_t brow = (size_t)(colbase + (tid >> 2)) * EMB;
    int    boff = (((tid & 3) ^ ((tid >> 3) & 3)) * 16);
    const char* gAh = (const char*)(wk_hi + arow) + boff;
    const char* gAl = (const char*)(wk_lo + arow) + boff;
    const char* gBh = (const char*)(wq_hi + brow) + boff;
    const char* gBl = (const char*)(wq_lo + brow) + boff;
    char* lAh = (char*)Ah_s + tid * 16;
    char* lAl = (char*)Al_s + tid * 16;
    char* lBh = (char*)Bh_s + tid * 16;
    char* lBl = (char*)Bl_s + tid * 16;

    for (int k0 = 0; k0 < EMB; k0 += BK) {
        __syncthreads();
        g2l16(gAh, lAh); g2l16(gAl, lAl);
        g2l16(gBh, lBh); g2l16(gBl, lBl);
        gAh += 64; gAl += 64; gBh += 64; gBl += 64;
        __syncthreads();

        half8 ah[2], al[2], bh[2], bl[2];
#pragma unroll
        for (int i = 0; i < 2; i++) {
            int roff = wrow + i * 16 + (lane & 15);
            int off = roff * 64 + ((((lane >> 4)) ^ ((roff >> 1) & 3)) * 16);
            ah[i] = *(const half8*)((const char*)Ah_s + off);
            al[i] = *(const half8*)((const char*)Al_s + off);
        }
#pragma unroll
        for (int j = 0; j < 2; j++) {
            int coff = wcol + j * 16 + (lane & 15);
            int off = coff * 64 + ((((lane >> 4)) ^ ((coff >> 1) & 3)) * 16);
            bh[j] = *(const half8*)((const char*)Bh_s + off);
            bl[j] = *(const half8*)((const char*)Bl_s + off);
        }
#pragma unroll
        for (int i = 0; i < 2; i++)
#pragma unroll
            for (int j = 0; j < 2; j++) {
                acc[i][j] = __builtin_amdgcn_mfma_f32_16x16x32_f16(ah[i], bh[j], acc[i][j], 0, 0, 0);
                acc[i][j] = __builtin_amdgcn_mfma_f32_16x16x32_f16(ah[i], bl[j], acc[i][j], 0, 0, 0);
                acc[i][j] = __builtin_amdgcn_mfma_f32_16x16x32_f16(al[i], bh[j], acc[i][j], 0, 0, 0);
            }
    }

#pragma unroll
    for (int j = 0; j < 2; j++) {
        int col = colbase + wcol + j * 16 + (lane & 15);
#pragma unroll
        for (int i = 0; i < 2; i++) {
#pragma unroll
            for (int r = 0; r < 4; r++) {
                int row = rowbase + wrow + i * 16 + (lane >> 4) * 4 + r;
                float v = acc[i][j][r];
                _Float16 hi = (_Float16)v;
                gt_cat[(size_t)row * 1536 + col]       = hi;
                gt_cat[(size_t)row * 1536 + 768 + col] = (_Float16)(v - (float)hi);
            }
        }
    }
}

// ---------------- t = hn @ Gcat^T, K=1536 stacked, scores-clone dbuf --------
__global__ __launch_bounds__(256) void t_kernel(
    const _Float16* __restrict__ hn_hi,
    const _Float16* __restrict__ gt_cat,
    _Float16* __restrict__ t_hi)
{
    __shared__ __attribute__((aligned(16))) _Float16 Ah_s[2][BM * BK2];
    __shared__ __attribute__((aligned(16))) _Float16 Bh_s[2][BN * BK2];

    // bijective XCD remap (nwg = 768, 768 % 8 == 0)
    int id  = (int)blockIdx.y * 6 + (int)blockIdx.x;
    int vid = (id & 7) * 96 + (id >> 3);
    int by  = vid / 6;
    int bx  = vid % 6;

    int rowbase = by * BM;
    int colbase = bx * BN;
    int tid  = threadIdx.x;
    int lane = tid & 63, wave = tid >> 6;
    int wrow = (wave >> 1) * 64, wcol = (wave & 1) * 64;

    floatx4 acc[4][4];
#pragma unroll
    for (int i = 0; i < 4; i++)
#pragma unroll
        for (int j = 0; j < 4; j++) acc[i][j] = (floatx4){0.f, 0.f, 0.f, 0.f};

    size_t arow = (size_t)(rowbase + tid / 8) * EMB;
    size_t brow = (size_t)(colbase + tid / 8) * 1536;
    int    boff = (((tid % 8) ^ ((tid >> 3) & 7)) * 16);
    const char* gA0 = (const char*)(hn_hi + arow) + boff;
    const char* gB0 = (const char*)(gt_cat + brow) + boff;
    const size_t pstrideA = (size_t)32 * EMB * 2;    // 32 rows of hn
    const size_t pstrideB = (size_t)32 * 1536 * 2;   // 32 rows of gt_cat

    auto STAGE = [&](int c, int kt) {
        const char* ga = gA0 + (kt % 12) * 128;      // hn k-offset wraps at 768
        const char* gb = gB0 + kt * 128;             // gcat k-offset 0..2944
        char* lA = (char*)Ah_s[c] + tid * 16;
        char* lB = (char*)Bh_s[c] + tid * 16;
#pragma unroll
        for (int p = 0; p < 4; p++) {
            g2l16(ga + p * pstrideA, lA + p * 4096);
            g2l16(gb + p * pstrideB, lB + p * 4096);
        }
    };

    const int NT = (2 * EMB) / BK2;   // 24
    STAGE(0, 0);
#pragma unroll 2
    for (int t = 0; t < NT; t++) {
        int cur = t & 1;
        asm volatile("" ::: "memory");
        if (t < NT - 1) {
            STAGE(cur ^ 1, t + 1);
            asm volatile("s_waitcnt vmcnt(8)" ::: "memory");
        } else {
            asm volatile("s_waitcnt vmcnt(0)" ::: "memory");
        }
        __builtin_amdgcn_s_barrier();
        asm volatile("" ::: "memory");

#pragma unroll
        for (int ko = 0; ko < 2; ko++) {
            half8 ah[4], bh[4];
#pragma unroll
            for (int i = 0; i < 4; i++) {
                int roff = wrow + i * 16 + (lane & 15);
                int off = roff * 128 + ((ko * 64 + (lane >> 4) * 16) ^ ((roff & 7) << 4));
                ah[i] = *(const half8*)((const char*)Ah_s[cur] + off);
            }
#pragma unroll
            for (int j = 0; j < 4; j++) {
                int coff = wcol + j * 16 + (lane & 15);
                int off = coff * 128 + ((ko * 64 + (lane >> 4) * 16) ^ ((coff & 7) << 4));
                bh[j] = *(const half8*)((const char*)Bh_s[cur] + off);
            }
#pragma unroll
            for (int i = 0; i < 4; i++)
#pragma unroll
                for (int j = 0; j < 4; j++)
                    acc[i][j] = __builtin_amdgcn_mfma_f32_16x16x32_f16(ah[i], bh[j], acc[i][j], 0, 0, 0);
        }
        asm volatile("" ::: "memory");
        __builtin_amdgcn_s_barrier();
    }

#pragma unroll
    for (int j = 0; j < 4; j++) {
        int col = colbase + wcol + j * 16 + (lane & 15);
#pragma unroll
        for (int i = 0; i < 4; i++) {
#pragma unroll
            for (int r = 0; r < 4; r++) {
                int row = rowbase + wrow + i * 16 + (lane >> 4) * 4 + r;
                t_hi[(size_t)row * EMB + col] = (_Float16)acc[i][j][r];
            }
        }
    }
}

// ---------------- scores: 128x128, BK=32, TRIPLE-buffered (depth-2 prefetch)
// LDS: 2 planes x 8 KB x 3 bufs = 48 KB (+1 KB red) -> 3 blocks/CU.
// Wait ladder: after STAGE(t+2) outstanding=12 -> vmcnt(8) == tile t done;
// t=NT-2: outstanding=8 -> vmcnt(4); t=NT-1: vmcnt(0). Prefetch distance
// = 2 iterations (~700 cy) > load latency. Staging/read swizzle = R3/R5
// verified BK=32 pattern (0 conflicts measured).
template<bool F16OUT>
__global__ __launch_bounds__(256) void scores_kernel(
    const _Float16* __restrict__ t_hi,
    const _Float16* __restrict__ hn_hi,
    const float* __restrict__ v_in,
    float* __restrict__ out,
    _Float16* __restrict__ pt,
    float2* __restrict__ state)
{
    __shared__ __attribute__((aligned(16))) _Float16 Ah_s[3][BM * BK];
    __shared__ __attribute__((aligned(16))) _Float16 Bh_s[3][BN * BK];
    __shared__ float red[128][2];

    int b = blockIdx.z;
    size_t base = (size_t)b * SEQ * EMB;
    int rowbase = blockIdx.y * BM;
    int colbase = blockIdx.x * BN;
    int tid  = threadIdx.x;
    int lane = tid & 63, wave = tid >> 6;
    int wrow = (wave >> 1) * 64, wcol = (wave & 1) * 64;

    floatx4 acc[4][4];
#pragma unroll
    for (int i = 0; i < 4; i++)
#pragma unroll
        for (int j = 0; j < 4; j++) acc[i][j] = (floatx4){0.f, 0.f, 0.f, 0.f};

    // staging: row tid/4 (+64 via half_stride), slot tid%4 holds global
    // chunk (tid%4) ^ ((r>>1)&3)  [(r>>1)&3 == (tid>>3)&3, invariant +64]
    size_t arow = base + (size_t)(rowbase + tid / 4) * EMB;
    size_t brow = base + (size_t)(colbase + tid / 4) * EMB;
    int    boff = (((tid & 3) ^ ((tid >> 3) & 3)) * 16);
    const char* gA0 = (const char*)(t_hi + arow) + boff;
    const char* gB0 = (const char*)(hn_hi + brow) + boff;
    const size_t half_stride = (size_t)64 * EMB * 2;

    auto STAGE = [&](int c, int kt) {
        const char* ga = gA0 + kt * 64;
        const char* gb = gB0 + kt * 64;
        char* lA = (char*)Ah_s[c] + tid * 16;
        char* lB = (char*)Bh_s[c] + tid * 16;
        g2l16(ga, lA); g2l16(ga + half_stride, lA + 4096);
        g2l16(gb, lB); g2l16(gb + half_stride, lB + 4096);
    };

    const int NT = EMB / BK;   // 24
    STAGE(0, 0);
    STAGE(1, 1);
#pragma unroll 3
    for (int t = 0; t < NT; t++) {
        int cur = t % 3;
        asm volatile("" ::: "memory");
        if (t < NT - 2) {
            STAGE((t + 2) % 3, t + 2);
            asm volatile("s_waitcnt vmcnt(8)" ::: "memory");
        } else if (t == NT - 2) {
            asm volatile("s_waitcnt vmcnt(4)" ::: "memory");
        } else {
            asm volatile("s_waitcnt vmcnt(0)" ::: "memory");
        }
        __builtin_amdgcn_s_barrier();
        asm volatile("" ::: "memory");

        half8 ah[4], bh[4];
#pragma unroll
        for (int i = 0; i < 4; i++) {
            int roff = wrow + i * 16 + (lane & 15);
            int off = roff * 64 + ((((lane >> 4)) ^ ((roff >> 1) & 3)) * 16);
            ah[i] = *(const half8*)((const char*)Ah_s[cur] + off);
        }
#pragma unroll
        for (int j = 0; j < 4; j++) {
            int coff = wcol + j * 16 + (lane & 15);
            int off = coff * 64 + ((((lane >> 4)) ^ ((coff >> 1) & 3)) * 16);
            bh[j] = *(const half8*)((const char*)Bh_s[cur] + off);
        }
        __builtin_amdgcn_s_setprio(1);
#pragma unroll
        for (int i = 0; i < 4; i++)
#pragma unroll
            for (int j = 0; j < 4; j++)
                acc[i][j] = __builtin_amdgcn_mfma_f32_16x16x32_f16(ah[i], bh[j], acc[i][j], 0, 0, 0);
        __builtin_amdgcn_s_setprio(0);
        asm volatile("" ::: "memory");
        __builtin_amdgcn_s_barrier();
    }

    // add column term v_c
    const float* vb = v_in + (size_t)b * SEQ + colbase;
#pragma unroll
    for (int j = 0; j < 4; j++) {
        float vv = vb[wcol + j * 16 + (lane & 15)];
#pragma unroll
        for (int i = 0; i < 4; i++)
#pragma unroll
            for (int r = 0; r < 4; r++) acc[i][j][r] += vv;
    }

    // ---- softmax partial epilogue ----
    float m1[4][4];
#pragma unroll
    for (int i = 0; i < 4; i++)
#pragma unroll
        for (int r = 0; r < 4; r++) {
            float m = fmaxf(fmaxf(acc[i][0][r], acc[i][1][r]), fmaxf(acc[i][2][r], acc[i][3][r]));
#pragma unroll
            for (int s = 1; s < 16; s <<= 1) m = fmaxf(m, __shfl_xor(m, s, 64));
            m1[i][r] = m;
        }
    if ((lane & 15) == 0) {
#pragma unroll
        for (int i = 0; i < 4; i++)
#pragma unroll
            for (int r = 0; r < 4; r++)
                red[wrow + i * 16 + (lane >> 4) * 4 + r][wave & 1] = m1[i][r];
    }
    __syncthreads();
    float mrow[4][4];
#pragma unroll
    for (int i = 0; i < 4; i++)
#pragma unroll
        for (int r = 0; r < 4; r++) {
            int rr = wrow + i * 16 + (lane >> 4) * 4 + r;
            mrow[i][r] = fmaxf(red[rr][0], red[rr][1]);
        }
    __syncthreads();

    float ls[4][4];
#pragma unroll
    for (int i = 0; i < 4; i++)
#pragma unroll
        for (int r = 0; r < 4; r++) {
            float s = 0.f;
#pragma unroll
            for (int j = 0; j < 4; j++) {
                float e = __expf(acc[i][j][r] - mrow[i][r]);
                acc[i][j][r] = e;
                s += e;
            }
#pragma unroll
            for (int sh = 1; sh < 16; sh <<= 1) s += __shfl_xor(s, sh, 64);
            ls[i][r] = s;
        }
    if ((lane & 15) == 0) {
#pragma unroll
        for (int i = 0; i < 4; i++)
#pragma unroll
            for (int r = 0; r < 4; r++)
                red[wrow + i * 16 + (lane >> 4) * 4 + r][wave & 1] = ls[i][r];
    }
    __syncthreads();

    // write ptilde (f16 when workspace permits, else f32)
    size_t outbase = (size_t)b * SEQ * SEQ;
#pragma unroll
    for (int i = 0; i < 4; i++)
#pragma unroll
        for (int j = 0; j < 4; j++)
#pragma unroll
            for (int r = 0; r < 4; r++) {
                int row = rowbase + wrow + i * 16 + (lane >> 4) * 4 + r;
                int col = colbase + wcol + j * 16 + (lane & 15);
                if (F16OUT)
                    pt[outbase + (size_t)row * SEQ + col] = (_Float16)acc[i][j][r];
                else
                    out[outbase + (size_t)row * SEQ + col] = acc[i][j][r];
            }

    // write per-(row, colblock) state
    if ((wave & 1) == 0 && (lane & 15) == 0) {
#pragma unroll
        for (int i = 0; i < 4; i++)
#pragma unroll
            for (int r = 0; r < 4; r++) {
                int rr = wrow + i * 16 + (lane >> 4) * 4 + r;
                float l = red[rr][0] + red[rr][1];
                state[((size_t)b * SEQ + rowbase + rr) * 16 + blockIdx.x] =
                    make_float2(mrow[i][r], l);
            }
    }
}

// ---------------- fixup: global softmax normalize (16 col-blocks) ----------
template<bool F16IN>
__global__ __launch_bounds__(256) void fixup_kernel(
    float* __restrict__ out,
    const _Float16* __restrict__ pt,
    const float2* __restrict__ state)
{
    int row  = blockIdx.x * 4 + (threadIdx.x >> 6);
    int lane = threadIdx.x & 63;
    float2 v = state[(size_t)row * 16 + (lane & 15)];
    float M = v.x;
#pragma unroll
    for (int s = 1; s < 16; s <<= 1) M = fmaxf(M, __shfl_xor(M, s, 64));
    float e  = __expf(v.x - M);
    float Lp = v.y * e;
#pragma unroll
    for (int s = 1; s < 16; s <<= 1) Lp += __shfl_xor(Lp, s, 64);
    float fv = e / Lp;          // per-column-block scale, held by lane t=lane&15

    if (F16IN) {
        const half8* p8 = (const half8*)(pt + (size_t)row * SEQ);
        float4* o4 = (float4*)(out + (size_t)row * SEQ);
#pragma unroll
        for (int c0 = 0; c0 < 4; c0++) {
            int i8 = c0 * 64 + lane;            // 8-elem chunk index, 0..255
            float s = __shfl(fv, i8 >> 4, 64);  // block = col/128 = i8/16
            half8 h = p8[i8];
            float4 a, bqv;
            a.x = (float)h[0] * s; a.y = (float)h[1] * s;
            a.z = (float)h[2] * s; a.w = (float)h[3] * s;
            bqv.x = (float)h[4] * s; bqv.y = (float)h[5] * s;
            bqv.z = (float)h[6] * s; bqv.w = (float)h[7] * s;
            o4[i8 * 2]     = a;
            o4[i8 * 2 + 1] = bqv;
        }
    } else {
        float4* o4 = (float4*)(out + (size_t)row * SEQ);
#pragma unroll
        for (int c0 = 0; c0 < 8; c0++) {
            int i4 = c0 * 64 + lane;
            float s = __shfl(fv, i4 >> 5, 64);
            float4 w = o4[i4];
            w.x *= s; w.y *= s; w.z *= s; w.w *= s;
            o4[i4] = w;
        }
    }
}

extern "C" void kernel_launch(void* const* d_in, const int* in_sizes, int n_in,
                              void* d_out, int out_size, void* d_ws, size_t ws_size,
                              hipStream_t stream)
{
    const float* h  = (const float*)d_in[0];
    const float* g  = (const float*)d_in[1];
    const float* be = (const float*)d_in[2];
    const float* wq = (const float*)d_in[3];
    const float* bq = (const float*)d_in[4];
    const float* wk = (const float*)d_in[5];
    const float* bk = (const float*)d_in[6];
    (void)bk;  // bk contributes only softmax-invariant row/const terms
    float* out = (float*)d_out;

    char* ws = (char*)d_ws;
    const size_t SZ  = (size_t)ROWS * EMB * 2;         // 25,165,824 B per 16384x768 f16 plane
    const size_t WSZ = (size_t)EMB * EMB * 2;          // 1,179,648 B per 768x768 f16 plane
    _Float16* hn_hi = (_Float16*)(ws);
    _Float16* t_hi  = (_Float16*)(ws + SZ);
    char* wbase = ws + 2 * SZ;
    _Float16* wq_hi = (_Float16*)(wbase);
    _Float16* wq_lo = (_Float16*)(wbase + WSZ);
    _Float16* wk_hi = (_Float16*)(wbase + 2 * WSZ);
    _Float16* wk_lo = (_Float16*)(wbase + 3 * WSZ);
    _Float16* gt_cat = (_Float16*)(wbase + 4 * WSZ);   // 768 x 1536 f16 (2*WSZ)
    char* sbase = wbase + 6 * WSZ;
    float*  wt = (float*)(sbase);                      // 768 f32
    float*  v  = (float*)(sbase + 4096);               // 16384 f32
    float2* st = (float2*)(sbase + 4096 + 65536);      // 2 MB
    char*   ptb = sbase + 4096 + 65536 + (size_t)ROWS * 16 * sizeof(float2);
    const size_t PTSZ = (size_t)BATCH * SEQ * SEQ * 2; // 64 MB f16 ptilde
    _Float16* pt = (_Float16*)ptb;
    bool use_f16 = ws_size >= (size_t)(ptb - ws) + PTSZ;

    split_w_kernel<<<dim3(576, 2), 256, 0, stream>>>(wq, wk, wq_hi, wq_lo, wk_hi, wk_lo);
    wtilde_kernel<<<dim3(EMB / 4), 256, 0, stream>>>(wk, bq, wt);
    ln_kernel<<<dim3(ROWS / 4), 256, 0, stream>>>(h, g, be, wt, hn_hi, v);
    gt_kernel<<<dim3(EMB / 64, EMB / 64), 256, 0, stream>>>(wk_hi, wk_lo, wq_hi, wq_lo, gt_cat);
    t_kernel<<<dim3(EMB / BN, ROWS / BM), 256, 0, stream>>>(hn_hi, gt_cat, t_hi);
    if (use_f16) {
        scores_kernel<true><<<dim3(SEQ / BN, SEQ / BM, BATCH), 256, 0, stream>>>(t_hi, hn_hi, v, out, pt, st);
        fixup_kernel<true><<<dim3(ROWS / 4), 256, 0, stream>>>(out, pt, st);
    } else {
        scores_kernel<false><<<dim3(SEQ / BN, SEQ / BM, BATCH), 256, 0, stream>>>(t_hi, hn_hi, v, out, nullptr, st);
        fixup_kernel<false><<<dim3(ROWS / 4), 256, 0, stream>>>(out, nullptr, st);
    }
}

// Round 11
// 351.976 us; speedup vs baseline: 1.0454x; 1.0454x over previous
//
#include <hip/hip_runtime.h>
#include <stdint.h>

#define EMB   768
#define BATCH 8
#define SEQ   2048
#define ROWS  (BATCH*SEQ)     // 16384
#define EPS   1e-5f

#define BM 128
#define BN 128
#define BK 32
#define BK2 64

typedef _Float16 half8 __attribute__((ext_vector_type(8)));
typedef _Float16 half4 __attribute__((ext_vector_type(4)));
typedef float    floatx4 __attribute__((ext_vector_type(4)));

// async global->LDS, 16B per lane (global_load_lds_dwordx4).
__device__ __forceinline__ void g2l16(const void* g, void* l) {
    __builtin_amdgcn_global_load_lds(
        (const __attribute__((address_space(1))) unsigned int*)g,
        (__attribute__((address_space(3))) unsigned int*)l,
        16, 0, 0);
}

// ---------------- prep: split weights (blocks 0..1151) + wtilde (1152..1343)
// split: f32 -> f16 hi/lo planes; wtilde = Wk @ bq. Branch is block-uniform.
__global__ __launch_bounds__(256) void prep_kernel(
    const float* __restrict__ wq, const float* __restrict__ wk,
    const float* __restrict__ bq,
    _Float16* __restrict__ wq_hi, _Float16* __restrict__ wq_lo,
    _Float16* __restrict__ wk_hi, _Float16* __restrict__ wk_lo,
    float* __restrict__ wt)
{
    int blk = blockIdx.x;
    if (blk < 1152) {
        int plane = blk >= 576;           // 0: wq, 1: wk
        int bx = plane ? blk - 576 : blk;
        const float* src = plane ? wk : wq;
        _Float16* dh     = plane ? wk_hi : wq_hi;
        _Float16* dl     = plane ? wk_lo : wq_lo;
        int i4 = bx * 256 + threadIdx.x;
        float4 v = ((const float4*)src)[i4];
        half4 vh, vl;
        float c[4] = {v.x, v.y, v.z, v.w};
#pragma unroll
        for (int t = 0; t < 4; t++) {
            _Float16 hi = (_Float16)c[t];
            vh[t] = hi;
            vl[t] = (_Float16)(c[t] - (float)hi);
        }
        ((half4*)dh)[i4] = vh;
        ((half4*)dl)[i4] = vl;
    } else {
        int row  = (blk - 1152) * 4 + (threadIdx.x >> 6);
        int lane = threadIdx.x & 63;
        const float4* r4 = (const float4*)(wk + (size_t)row * EMB);
        const float4* b4 = (const float4*)bq;
        float s = 0.f;
#pragma unroll
        for (int j = 0; j < 3; j++) {
            float4 a = r4[lane + j * 64];
            float4 b = b4[lane + j * 64];
            s += a.x * b.x + a.y * b.y + a.z * b.z + a.w * b.w;
        }
#pragma unroll
        for (int sh = 1; sh < 64; sh <<= 1) s += __shfl_xor(s, sh, 64);
        if (lane == 0) wt[row] = s;
    }
}

// ---------------- LayerNorm: f32 in -> f16 hi only, + v = hn . wtilde -------
__global__ __launch_bounds__(256) void ln_kernel(
    const float* __restrict__ h,
    const float* __restrict__ gamma,
    const float* __restrict__ beta,
    const float* __restrict__ wt,
    _Float16* __restrict__ hn_hi,
    float* __restrict__ v_out)
{
    int row  = blockIdx.x * 4 + (threadIdx.x >> 6);
    int lane = threadIdx.x & 63;
    const float4* hr4 = (const float4*)(h + (size_t)row * EMB);
    float4 x[3];
    float s1 = 0.f, s2 = 0.f;
#pragma unroll
    for (int j = 0; j < 3; j++) {
        x[j] = hr4[lane + j * 64];
        s1 += x[j].x + x[j].y + x[j].z + x[j].w;
        s2 += x[j].x * x[j].x + x[j].y * x[j].y + x[j].z * x[j].z + x[j].w * x[j].w;
    }
#pragma unroll
    for (int s = 1; s < 64; s <<= 1) {
        s1 += __shfl_xor(s1, s, 64);
        s2 += __shfl_xor(s2, s, 64);
    }
    float mu  = s1 * (1.0f / EMB);
    float var = s2 * (1.0f / EMB) - mu * mu;
    float rs  = rsqrtf(var + EPS);
    _Float16* oh = hn_hi + (size_t)row * EMB;
    float vsum = 0.f;
#pragma unroll
    for (int j = 0; j < 3; j++) {
        int e4 = lane + j * 64;
        float4 g = ((const float4*)gamma)[e4];
        float4 b = ((const float4*)beta)[e4];
        float4 w = ((const float4*)wt)[e4];
        float v[4] = {
            (x[j].x - mu) * rs * g.x + b.x,
            (x[j].y - mu) * rs * g.y + b.y,
            (x[j].z - mu) * rs * g.z + b.z,
            (x[j].w - mu) * rs * g.w + b.w };
        vsum += v[0] * w.x + v[1] * w.y + v[2] * w.z + v[3] * w.w;
        half4 vh;
#pragma unroll
        for (int t = 0; t < 4; t++) vh[t] = (_Float16)v[t];
        *(half4*)(oh + e4 * 4) = vh;
    }
#pragma unroll
    for (int s = 1; s < 64; s <<= 1) vsum += __shfl_xor(vsum, s, 64);
    if (lane == 0) v_out[row] = vsum;
}

// ---------------- GT = Wk @ Wq^T, 64x64 tiles, DBUF (R2 skeleton, vmcnt(4)) -
// Output -> concatenated rows: gt_cat row j (1536): [hi row j | lo row j].
__global__ __launch_bounds__(256) void gt_kernel(
    const _Float16* __restrict__ wk_hi, const _Float16* __restrict__ wk_lo,
    const _Float16* __restrict__ wq_hi, const _Float16* __restrict__ wq_lo,
    _Float16* __restrict__ gt_cat)
{
    __shared__ __attribute__((aligned(16))) _Float16 Ah_s[2][64 * BK];
    __shared__ __attribute__((aligned(16))) _Float16 Al_s[2][64 * BK];
    __shared__ __attribute__((aligned(16))) _Float16 Bh_s[2][64 * BK];
    __shared__ __attribute__((aligned(16))) _Float16 Bl_s[2][64 * BK];

    int rowbase = blockIdx.y * 64;
    int colbase = blockIdx.x * 64;
    int tid  = threadIdx.x;
    int lane = tid & 63, wave = tid >> 6;
    int wrow = (wave >> 1) * 32, wcol = (wave & 1) * 32;

    floatx4 acc[2][2];
#pragma unroll
    for (int i = 0; i < 2; i++)
#pragma unroll
        for (int j = 0; j < 2; j++) acc[i][j] = (floatx4){0.f, 0.f, 0.f, 0.f};

    size_t arow = (size_t)(rowbase + (tid >> 2)) * EMB;
    size_t brow = (size_t)(colbase + (tid >> 2)) * EMB;
    int    boff = (((tid & 3) ^ ((tid >> 3) & 3)) * 16);
    const char* gAh = (const char*)(wk_hi + arow) + boff;
    const char* gAl = (const char*)(wk_lo + arow) + boff;
    const char* gBh = (const char*)(wq_hi + brow) + boff;
    const char* gBl = (const char*)(wq_lo + brow) + boff;

    auto STAGE = [&](int c, int kt) {
        char* lAh = (char*)Ah_s[c] + tid * 16;
        char* lAl = (char*)Al_s[c] + tid * 16;
        char* lBh = (char*)Bh_s[c] + tid * 16;
        char* lBl = (char*)Bl_s[c] + tid * 16;
        g2l16(gAh + kt * 64, lAh); g2l16(gAl + kt * 64, lAl);
        g2l16(gBh + kt * 64, lBh); g2l16(gBl + kt * 64, lBl);
    };

    const int NT = EMB / BK;   // 24
    STAGE(0, 0);
#pragma unroll 2
    for (int t = 0; t < NT; t++) {
        int cur = t & 1;
        asm volatile("" ::: "memory");
        if (t < NT - 1) {
            STAGE(cur ^ 1, t + 1);
            asm volatile("s_waitcnt vmcnt(4)" ::: "memory");
        } else {
            asm volatile("s_waitcnt vmcnt(0)" ::: "memory");
        }
        __builtin_amdgcn_s_barrier();
        asm volatile("" ::: "memory");

        half8 ah[2], al[2], bh[2], bl[2];
#pragma unroll
        for (int i = 0; i < 2; i++) {
            int roff = wrow + i * 16 + (lane & 15);
            int off = roff * 64 + ((((lane >> 4)) ^ ((roff >> 1) & 3)) * 16);
            ah[i] = *(const half8*)((const char*)Ah_s[cur] + off);
            al[i] = *(const half8*)((const char*)Al_s[cur] + off);
        }
#pragma unroll
        for (int j = 0; j < 2; j++) {
            int coff = wcol + j * 16 + (lane & 15);
            int off = coff * 64 + ((((lane >> 4)) ^ ((coff >> 1) & 3)) * 16);
            bh[j] = *(const half8*)((const char*)Bh_s[cur] + off);
            bl[j] = *(const half8*)((const char*)Bl_s[cur] + off);
        }
#pragma unroll
        for (int i = 0; i < 2; i++)
#pragma unroll
            for (int j = 0; j < 2; j++) {
                acc[i][j] = __builtin_amdgcn_mfma_f32_16x16x32_f16(ah[i], bh[j], acc[i][j], 0, 0, 0);
                acc[i][j] = __builtin_amdgcn_mfma_f32_16x16x32_f16(ah[i], bl[j], acc[i][j], 0, 0, 0);
                acc[i][j] = __builtin_amdgcn_mfma_f32_16x16x32_f16(al[i], bh[j], acc[i][j], 0, 0, 0);
            }
        asm volatile("" ::: "memory");
        __builtin_amdgcn_s_barrier();
    }

#pragma unroll
    for (int j = 0; j < 2; j++) {
        int col = colbase + wcol + j * 16 + (lane & 15);
#pragma unroll
        for (int i = 0; i < 2; i++) {
#pragma unroll
            for (int r = 0; r < 4; r++) {
                int row = rowbase + wrow + i * 16 + (lane >> 4) * 4 + r;
                float v = acc[i][j][r];
                _Float16 hi = (_Float16)v;
                gt_cat[(size_t)row * 1536 + col]       = hi;
                gt_cat[(size_t)row * 1536 + 768 + col] = (_Float16)(v - (float)hi);
            }
        }
    }
}

// ---------------- t = hn @ Gcat^T, K=1536 stacked, scores-clone dbuf --------
__global__ __launch_bounds__(256) void t_kernel(
    const _Float16* __restrict__ hn_hi,
    const _Float16* __restrict__ gt_cat,
    _Float16* __restrict__ t_hi)
{
    __shared__ __attribute__((aligned(16))) _Float16 Ah_s[2][BM * BK2];
    __shared__ __attribute__((aligned(16))) _Float16 Bh_s[2][BN * BK2];

    // bijective XCD remap (nwg = 768, 768 % 8 == 0)
    int id  = (int)blockIdx.y * 6 + (int)blockIdx.x;
    int vid = (id & 7) * 96 + (id >> 3);
    int by  = vid / 6;
    int bx  = vid % 6;

    int rowbase = by * BM;
    int colbase = bx * BN;
    int tid  = threadIdx.x;
    int lane = tid & 63, wave = tid >> 6;
    int wrow = (wave >> 1) * 64, wcol = (wave & 1) * 64;

    floatx4 acc[4][4];
#pragma unroll
    for (int i = 0; i < 4; i++)
#pragma unroll
        for (int j = 0; j < 4; j++) acc[i][j] = (floatx4){0.f, 0.f, 0.f, 0.f};

    size_t arow = (size_t)(rowbase + tid / 8) * EMB;
    size_t brow = (size_t)(colbase + tid / 8) * 1536;
    int    boff = (((tid % 8) ^ ((tid >> 3) & 7)) * 16);
    const char* gA0 = (const char*)(hn_hi + arow) + boff;
    const char* gB0 = (const char*)(gt_cat + brow) + boff;
    const size_t pstrideA = (size_t)32 * EMB * 2;    // 32 rows of hn
    const size_t pstrideB = (size_t)32 * 1536 * 2;   // 32 rows of gt_cat

    auto STAGE = [&](int c, int kt) {
        const char* ga = gA0 + (kt % 12) * 128;      // hn k-offset wraps at 768
        const char* gb = gB0 + kt * 128;             // gcat k-offset 0..2944
        char* lA = (char*)Ah_s[c] + tid * 16;
        char* lB = (char*)Bh_s[c] + tid * 16;
#pragma unroll
        for (int p = 0; p < 4; p++) {
            g2l16(ga + p * pstrideA, lA + p * 4096);
            g2l16(gb + p * pstrideB, lB + p * 4096);
        }
    };

    const int NT = (2 * EMB) / BK2;   // 24
    STAGE(0, 0);
#pragma unroll 2
    for (int t = 0; t < NT; t++) {
        int cur = t & 1;
        asm volatile("" ::: "memory");
        if (t < NT - 1) {
            STAGE(cur ^ 1, t + 1);
            asm volatile("s_waitcnt vmcnt(8)" ::: "memory");
        } else {
            asm volatile("s_waitcnt vmcnt(0)" ::: "memory");
        }
        __builtin_amdgcn_s_barrier();
        asm volatile("" ::: "memory");

#pragma unroll
        for (int ko = 0; ko < 2; ko++) {
            half8 ah[4], bh[4];
#pragma unroll
            for (int i = 0; i < 4; i++) {
                int roff = wrow + i * 16 + (lane & 15);
                int off = roff * 128 + ((ko * 64 + (lane >> 4) * 16) ^ ((roff & 7) << 4));
                ah[i] = *(const half8*)((const char*)Ah_s[cur] + off);
            }
#pragma unroll
            for (int j = 0; j < 4; j++) {
                int coff = wcol + j * 16 + (lane & 15);
                int off = coff * 128 + ((ko * 64 + (lane >> 4) * 16) ^ ((coff & 7) << 4));
                bh[j] = *(const half8*)((const char*)Bh_s[cur] + off);
            }
#pragma unroll
            for (int i = 0; i < 4; i++)
#pragma unroll
                for (int j = 0; j < 4; j++)
                    acc[i][j] = __builtin_amdgcn_mfma_f32_16x16x32_f16(ah[i], bh[j], acc[i][j], 0, 0, 0);
        }
        asm volatile("" ::: "memory");
        __builtin_amdgcn_s_barrier();
    }

#pragma unroll
    for (int j = 0; j < 4; j++) {
        int col = colbase + wcol + j * 16 + (lane & 15);
#pragma unroll
        for (int i = 0; i < 4; i++) {
#pragma unroll
            for (int r = 0; r < 4; r++) {
                int row = rowbase + wrow + i * 16 + (lane >> 4) * 4 + r;
                t_hi[(size_t)row * EMB + col] = (_Float16)acc[i][j][r];
            }
        }
    }
}

// ---------------- scores: R2-exact 128x128 BK=64 dbuf, counted vmcnt(8) ----
template<bool F16OUT>
__global__ __launch_bounds__(256) void scores_kernel(
    const _Float16* __restrict__ t_hi,
    const _Float16* __restrict__ hn_hi,
    const float* __restrict__ v_in,
    float* __restrict__ out,
    _Float16* __restrict__ pt,
    float2* __restrict__ state)
{
    __shared__ __attribute__((aligned(16))) _Float16 Ah_s[2][BM * BK2];
    __shared__ __attribute__((aligned(16))) _Float16 Bh_s[2][BN * BK2];
    __shared__ float red[128][2];

    int b = blockIdx.z;
    size_t base = (size_t)b * SEQ * EMB;
    int rowbase = blockIdx.y * BM;
    int colbase = blockIdx.x * BN;
    int tid  = threadIdx.x;
    int lane = tid & 63, wave = tid >> 6;
    int wrow = (wave >> 1) * 64, wcol = (wave & 1) * 64;

    floatx4 acc[4][4];
#pragma unroll
    for (int i = 0; i < 4; i++)
#pragma unroll
        for (int j = 0; j < 4; j++) acc[i][j] = (floatx4){0.f, 0.f, 0.f, 0.f};

    size_t arow = base + (size_t)(rowbase + tid / 8) * EMB;
    size_t brow = base + (size_t)(colbase + tid / 8) * EMB;
    int    boff = (((tid % 8) ^ ((tid >> 3) & 7)) * 16);
    const char* gAh = (const char*)(t_hi + arow) + boff;
    const char* gBh = (const char*)(hn_hi + brow) + boff;
    char* lAh0 = (char*)Ah_s[0] + tid * 16;
    char* lBh0 = (char*)Bh_s[0] + tid * 16;
    char* lAh1 = (char*)Ah_s[1] + tid * 16;
    char* lBh1 = (char*)Bh_s[1] + tid * 16;
    const size_t pstride = (size_t)32 * EMB * 2;

    auto STAGE = [&](int c) {
        char* lA = c ? lAh1 : lAh0;
        char* lB = c ? lBh1 : lBh0;
#pragma unroll
        for (int p = 0; p < 4; p++) {
            g2l16(gAh + p * pstride, lA + p * 4096);
            g2l16(gBh + p * pstride, lB + p * 4096);
        }
        gAh += 128; gBh += 128;
    };

    const int NT = EMB / BK2;   // 12
    STAGE(0);
#pragma unroll 2
    for (int t = 0; t < NT; t++) {
        int cur = t & 1;
        asm volatile("" ::: "memory");
        if (t < NT - 1) {
            STAGE(cur ^ 1);
            asm volatile("s_waitcnt vmcnt(8)" ::: "memory");
        } else {
            asm volatile("s_waitcnt vmcnt(0)" ::: "memory");
        }
        __builtin_amdgcn_s_barrier();
        asm volatile("" ::: "memory");

#pragma unroll
        for (int ko = 0; ko < 2; ko++) {
            half8 ah[4], bh[4];
#pragma unroll
            for (int i = 0; i < 4; i++) {
                int roff = wrow + i * 16 + (lane & 15);
                int off = roff * 128 + ((ko * 64 + (lane >> 4) * 16) ^ ((roff & 7) << 4));
                ah[i] = *(const half8*)((const char*)Ah_s[cur] + off);
            }
#pragma unroll
            for (int j = 0; j < 4; j++) {
                int coff = wcol + j * 16 + (lane & 15);
                int off = coff * 128 + ((ko * 64 + (lane >> 4) * 16) ^ ((coff & 7) << 4));
                bh[j] = *(const half8*)((const char*)Bh_s[cur] + off);
            }
#pragma unroll
            for (int i = 0; i < 4; i++)
#pragma unroll
                for (int j = 0; j < 4; j++)
                    acc[i][j] = __builtin_amdgcn_mfma_f32_16x16x32_f16(ah[i], bh[j], acc[i][j], 0, 0, 0);
        }
        asm volatile("" ::: "memory");
        __builtin_amdgcn_s_barrier();
    }

    // add column term v_c
    const float* vb = v_in + (size_t)b * SEQ + colbase;
#pragma unroll
    for (int j = 0; j < 4; j++) {
        float vv = vb[wcol + j * 16 + (lane & 15)];
#pragma unroll
        for (int i = 0; i < 4; i++)
#pragma unroll
            for (int r = 0; r < 4; r++) acc[i][j][r] += vv;
    }

    // ---- softmax partial epilogue ----
    float m1[4][4];
#pragma unroll
    for (int i = 0; i < 4; i++)
#pragma unroll
        for (int r = 0; r < 4; r++) {
            float m = fmaxf(fmaxf(acc[i][0][r], acc[i][1][r]), fmaxf(acc[i][2][r], acc[i][3][r]));
#pragma unroll
            for (int s = 1; s < 16; s <<= 1) m = fmaxf(m, __shfl_xor(m, s, 64));
            m1[i][r] = m;
        }
    if ((lane & 15) == 0) {
#pragma unroll
        for (int i = 0; i < 4; i++)
#pragma unroll
            for (int r = 0; r < 4; r++)
                red[wrow + i * 16 + (lane >> 4) * 4 + r][wave & 1] = m1[i][r];
    }
    __syncthreads();
    float mrow[4][4];
#pragma unroll
    for (int i = 0; i < 4; i++)
#pragma unroll
        for (int r = 0; r < 4; r++) {
            int rr = wrow + i * 16 + (lane >> 4) * 4 + r;
            mrow[i][r] = fmaxf(red[rr][0], red[rr][1]);
        }
    __syncthreads();

    float ls[4][4];
#pragma unroll
    for (int i = 0; i < 4; i++)
#pragma unroll
        for (int r = 0; r < 4; r++) {
            float s = 0.f;
#pragma unroll
            for (int j = 0; j < 4; j++) {
                float e = __expf(acc[i][j][r] - mrow[i][r]);
                acc[i][j][r] = e;
                s += e;
            }
#pragma unroll
            for (int sh = 1; sh < 16; sh <<= 1) s += __shfl_xor(s, sh, 64);
            ls[i][r] = s;
        }
    if ((lane & 15) == 0) {
#pragma unroll
        for (int i = 0; i < 4; i++)
#pragma unroll
            for (int r = 0; r < 4; r++)
                red[wrow + i * 16 + (lane >> 4) * 4 + r][wave & 1] = ls[i][r];
    }
    __syncthreads();

    // write ptilde (f16 when workspace permits, else f32)
    size_t outbase = (size_t)b * SEQ * SEQ;
#pragma unroll
    for (int i = 0; i < 4; i++)
#pragma unroll
        for (int j = 0; j < 4; j++)
#pragma unroll
            for (int r = 0; r < 4; r++) {
                int row = rowbase + wrow + i * 16 + (lane >> 4) * 4 + r;
                int col = colbase + wcol + j * 16 + (lane & 15);
                if (F16OUT)
                    pt[outbase + (size_t)row * SEQ + col] = (_Float16)acc[i][j][r];
                else
                    out[outbase + (size_t)row * SEQ + col] = acc[i][j][r];
            }

    // write per-(row, colblock) state
    if ((wave & 1) == 0 && (lane & 15) == 0) {
#pragma unroll
        for (int i = 0; i < 4; i++)
#pragma unroll
            for (int r = 0; r < 4; r++) {
                int rr = wrow + i * 16 + (lane >> 4) * 4 + r;
                float l = red[rr][0] + red[rr][1];
                state[((size_t)b * SEQ + rowbase + rr) * 16 + blockIdx.x] =
                    make_float2(mrow[i][r], l);
            }
    }
}

// ---------------- fixup: global softmax normalize (16 col-blocks) ----------
template<bool F16IN>
__global__ __launch_bounds__(256) void fixup_kernel(
    float* __restrict__ out,
    const _Float16* __restrict__ pt,
    const float2* __restrict__ state)
{
    int row  = blockIdx.x * 4 + (threadIdx.x >> 6);
    int lane = threadIdx.x & 63;
    float2 v = state[(size_t)row * 16 + (lane & 15)];
    float M = v.x;
#pragma unroll
    for (int s = 1; s < 16; s <<= 1) M = fmaxf(M, __shfl_xor(M, s, 64));
    float e  = __expf(v.x - M);
    float Lp = v.y * e;
#pragma unroll
    for (int s = 1; s < 16; s <<= 1) Lp += __shfl_xor(Lp, s, 64);
    float fv = e / Lp;          // per-column-block scale, held by lane t=lane&15

    if (F16IN) {
        const half8* p8 = (const half8*)(pt + (size_t)row * SEQ);
        float4* o4 = (float4*)(out + (size_t)row * SEQ);
#pragma unroll
        for (int c0 = 0; c0 < 4; c0++) {
            int i8 = c0 * 64 + lane;            // 8-elem chunk index, 0..255
            float s = __shfl(fv, i8 >> 4, 64);  // block = col/128 = i8/16
            half8 h = p8[i8];
            float4 a, bqv;
            a.x = (float)h[0] * s; a.y = (float)h[1] * s;
            a.z = (float)h[2] * s; a.w = (float)h[3] * s;
            bqv.x = (float)h[4] * s; bqv.y = (float)h[5] * s;
            bqv.z = (float)h[6] * s; bqv.w = (float)h[7] * s;
            o4[i8 * 2]     = a;
            o4[i8 * 2 + 1] = bqv;
        }
    } else {
        float4* o4 = (float4*)(out + (size_t)row * SEQ);
#pragma unroll
        for (int c0 = 0; c0 < 8; c0++) {
            int i4 = c0 * 64 + lane;
            float s = __shfl(fv, i4 >> 5, 64);
            float4 w = o4[i4];
            w.x *= s; w.y *= s; w.z *= s; w.w *= s;
            o4[i4] = w;
        }
    }
}

extern "C" void kernel_launch(void* const* d_in, const int* in_sizes, int n_in,
                              void* d_out, int out_size, void* d_ws, size_t ws_size,
                              hipStream_t stream)
{
    const float* h  = (const float*)d_in[0];
    const float* g  = (const float*)d_in[1];
    const float* be = (const float*)d_in[2];
    const float* wq = (const float*)d_in[3];
    const float* bq = (const float*)d_in[4];
    const float* wk = (const float*)d_in[5];
    const float* bk = (const float*)d_in[6];
    (void)bk;  // bk contributes only softmax-invariant row/const terms
    float* out = (float*)d_out;

    char* ws = (char*)d_ws;
    const size_t SZ  = (size_t)ROWS * EMB * 2;         // 25,165,824 B per 16384x768 f16 plane
    const size_t WSZ = (size_t)EMB * EMB * 2;          // 1,179,648 B per 768x768 f16 plane
    _Float16* hn_hi = (_Float16*)(ws);
    _Float16* t_hi  = (_Float16*)(ws + SZ);
    char* wbase = ws + 2 * SZ;
    _Float16* wq_hi = (_Float16*)(wbase);
    _Float16* wq_lo = (_Float16*)(wbase + WSZ);
    _Float16* wk_hi = (_Float16*)(wbase + 2 * WSZ);
    _Float16* wk_lo = (_Float16*)(wbase + 3 * WSZ);
    _Float16* gt_cat = (_Float16*)(wbase + 4 * WSZ);   // 768 x 1536 f16 (2*WSZ)
    char* sbase = wbase + 6 * WSZ;
    float*  wt = (float*)(sbase);                      // 768 f32
    float*  v  = (float*)(sbase + 4096);               // 16384 f32
    float2* st = (float2*)(sbase + 4096 + 65536);      // 2 MB
    char*   ptb = sbase + 4096 + 65536 + (size_t)ROWS * 16 * sizeof(float2);
    const size_t PTSZ = (size_t)BATCH * SEQ * SEQ * 2; // 64 MB f16 ptilde
    _Float16* pt = (_Float16*)ptb;
    bool use_f16 = ws_size >= (size_t)(ptb - ws) + PTSZ;

    prep_kernel<<<dim3(1344), 256, 0, stream>>>(wq, wk, bq, wq_hi, wq_lo, wk_hi, wk_lo, wt);
    ln_kernel<<<dim3(ROWS / 4), 256, 0, stream>>>(h, g, be, wt, hn_hi, v);
    gt_kernel<<<dim3(EMB / 64, EMB / 64), 256, 0, stream>>>(wk_hi, wk_lo, wq_hi, wq_lo, gt_cat);
    t_kernel<<<dim3(EMB / BN, ROWS / BM), 256, 0, stream>>>(hn_hi, gt_cat, t_hi);
    if (use_f16) {
        scores_kernel<true><<<dim3(SEQ / BN, SEQ / BM, BATCH), 256, 0, stream>>>(t_hi, hn_hi, v, out, pt, st);
        fixup_kernel<true><<<dim3(ROWS / 4), 256, 0, stream>>>(out, pt, st);
    } else {
        scores_kernel<false><<<dim3(SEQ / BN, SEQ / BM, BATCH), 256, 0, stream>>>(t_hi, hn_hi, v, out, nullptr, st);
        fixup_kernel<false><<<dim3(ROWS / 4), 256, 0, stream>>>(out, nullptr, st);
    }
}